// Round 5
// baseline (136.933 us; speedup 1.0000x reference)
//
#include <hip/hip_runtime.h>
#include <cmath>

// Problem constants (B=4096, D=256, P=100, K=10, n=2B=8192, T=0.2)
#define BB   4096
#define DD   256
#define NN   8192
#define PP   100
#define KK   10

typedef float f32x16 __attribute__((ext_vector_type(16)));
typedef long  lx2    __attribute__((ext_vector_type(2)));

// ---------------- workspace layout (bytes) ----------------
// R19: dpart/ppart padded to 512 slots (one double per 64B line) to kill
// cross-XCD atomic line ping-pong. sim's lines are XCD-partitioned.
// R20: counting sort REMOVED. Every consumer is class-indexed: the flat
// hard_q input IS the class-at-position array (hq.reshape(-1)), so sim/ctab
// read hq directly, norm writes Gpb at p=i. prep = zero accs + histogram only
// (protopd needs cnt). Cost was ~7us of one-CU scattered stores + invp/pi
// indirection on the serial chain; benefit was only L2-resident gather
// locality in sim's epilogue.
constexpr size_t OFF_DPART = 0;        // 512 double (64B-line stride)
constexpr size_t OFF_PPART = 4096;     // 512 double
constexpr size_t OFF_CNT   = 8192;     // 100 int
constexpr size_t OFF_MU    = 8704;     // 100 f32
constexpr size_t OFF_SD    = 9216;     // 100 f32
constexpr size_t OFF_RWN   = 9728;     // 10000 f32 -> 49728
constexpr size_t OFF_CTABT = 49728;    // 100*8192 f32 -> 3326528 (16B aligned)
constexpr size_t OFF_G     = 3326528;  // 8192*256 fp8 pair-packed (2 MB), 16B aligned

// Pair-packed fp8 G layout for mfma_f32_32x32x16_fp8_fp8 (byte addr):
// element (row p, k) at (p>>5)*8192 + (k>>5)*1024 + (((k>>3)&1)*32 + (p&31))*16
//                     + ((k>>4)&1)*8 + (k&7)
// => lane l's fragments for kc=2q,2q+1 are the contiguous 16 B at
//    (p>>5)*8192 + q*1024 + l*16   (low 8 B: kc=2q, high 8 B: kc=2q+1)

// ------ prep (1 block): zero accumulators + class histogram -> cnt ------
__global__ __launch_bounds__(1024) void prep_kernel(
    const int* __restrict__ hq, int* __restrict__ cnt,
    double* __restrict__ dpart, double* __restrict__ ppart) {
    __shared__ int h[16][PP];
    const int t = threadIdx.x;   // 1024
    const int wv = t >> 6;
    h[t & 15][t >> 4] = 0;       // zero 16x100 = 1600 slots in 2 passes
    if (t < 576) h[(t + 1024) & 15][(t + 1024) >> 4] = 0;
    if (t < 512) dpart[t] = 0.0; else ppart[t - 512] = 0.0;
    __syncthreads();
#pragma unroll
    for (int r = 0; r < 8; ++r) atomicAdd(&h[wv][hq[r * 1024 + t]], 1);
    __syncthreads();
    if (t < PP) {
        int s = 0;
#pragma unroll
        for (int w = 0; w < 16; ++w) s += h[w][t];
        cnt[t] = s;
    }
}

// ---- merged: blocks 0..1023 normalize (wave/sample); blocks 1024..1123 protopd ----
__global__ __launch_bounds__(256) void norm_protopd_kernel(
    const float* __restrict__ x, const float* __restrict__ xa,
    const float* __restrict__ pw,
    const int* __restrict__ cnt, char* __restrict__ Gpb, double* __restrict__ ppart,
    float* __restrict__ rwn, float* __restrict__ mu, float* __restrict__ sd) {
    const int blk = blockIdx.x;
    const int t = threadIdx.x;
    if (blk < 1024) {
        // ---- normalize role: wave per sample, barrier-free ----
        const int wv = t >> 6, lane = t & 63;
        const int i = blk * 4 + wv;            // sample 0..4095
        const float4 v1 = *(const float4*)(x  + (size_t)i * DD + lane * 4);
        const float4 v2 = *(const float4*)(xa + (size_t)i * DD + lane * 4);
        float a = v1.x * v1.x + v1.y * v1.y + v1.z * v1.z + v1.w * v1.w;
        float b = v2.x * v2.x + v2.y * v2.y + v2.z * v2.z + v2.w * v2.w;
        float c = v1.x * v2.x + v1.y * v2.y + v1.z * v2.z + v1.w * v2.w;
#pragma unroll
        for (int off = 32; off > 0; off >>= 1) {
            a += __shfl_xor(a, off);
            b += __shfl_xor(b, off);
            c += __shfl_xor(c, off);
        }
        const float d1 = fmaxf(sqrtf(a), 1e-12f), i1 = 1.0f / d1;
        const float d2 = fmaxf(sqrtf(b), 1e-12f), i2 = 1.0f / d2;
        const int p1 = i;         // R20: orig index IS the position (no sort)
        const int p2 = i + BB;
        int w1 = __builtin_amdgcn_cvt_pk_fp8_f32(v1.x * i1, v1.y * i1, 0, false);
        w1 = __builtin_amdgcn_cvt_pk_fp8_f32(v1.z * i1, v1.w * i1, w1, true);
        int w2 = __builtin_amdgcn_cvt_pk_fp8_f32(v2.x * i2, v2.y * i2, 0, false);
        w2 = __builtin_amdgcn_cvt_pk_fp8_f32(v2.z * i2, v2.w * i2, w2, true);
        // lane l holds k0 = 4l: q=k0>>5, halfsel=(k0>>3)&1, pairsel=(k0>>4)&1
        const int q = lane >> 3, halfsel = (lane >> 1) & 1, pairsel = (lane >> 2) & 1;
        const int bo = pairsel * 8 + 4 * (lane & 1);
        const size_t a1 = (size_t)((p1 >> 5) * 8192 + q * 1024 +
                                   (halfsel * 32 + (p1 & 31)) * 16 + bo);
        const size_t a2 = (size_t)((p2 >> 5) * 8192 + q * 1024 +
                                   (halfsel * 32 + (p2 & 31)) * 16 + bo);
        *(int*)(Gpb + a1) = w1;
        *(int*)(Gpb + a2) = w2;
        // R19: one double per 64B line
        if (lane == 0) atomicAdd(&ppart[i & 511], (double)(c * i1 * i2));
    } else {
        // ---- protopd role: proto-norm row a + pd row + per-class stats ----
        const int a = blk - 1024;   // 0..99
        __shared__ alignas(16) float wa[DD];
        __shared__ float pdrow[PP];
        __shared__ float r4[4];
        float av = pw[(size_t)a * DD + t];
        float ss = av * av;
#pragma unroll
        for (int off = 32; off > 0; off >>= 1) ss += __shfl_down(ss, off);
        if ((t & 63) == 0) r4[t >> 6] = ss;
        __syncthreads();
        const float na = fmaxf(sqrtf(r4[0] + r4[1] + r4[2] + r4[3]), 1e-12f);
        wa[t] = av / na;
        __syncthreads();
        if (t < PP) {
            const float4* wc = (const float4*)(pw + (size_t)t * DD);
            float dot = 0.f, nb = 0.f;
#pragma unroll 4
            for (int k = 0; k < 64; ++k) {
                const float4 w = wc[k];
                const float4 u = *(const float4*)(wa + 4 * k);
                dot += u.x * w.x + u.y * w.y + u.z * w.z + u.w * w.w;
                nb += w.x * w.x + w.y * w.y + w.z * w.z + w.w * w.w;
            }
            pdrow[t] = 1.0f - dot / fmaxf(sqrtf(nb), 1e-12f);
        }
        __syncthreads();
        if (t < 64) {
            const int lane = t;
            float vmin = 0.f, vmax = 0.f;  // eye-zero always in multiset
            for (int b = lane; b < PP; b += 64) {
                int cc = cnt[b] - (b == a ? 1 : 0);
                if (cc > 0) {
                    float v = pdrow[b];
                    vmin = fminf(vmin, v);
                    vmax = fmaxf(vmax, v);
                }
            }
#pragma unroll
            for (int off = 32; off > 0; off >>= 1) {
                vmin = fminf(vmin, __shfl_xor(vmin, off));
                vmax = fmaxf(vmax, __shfl_xor(vmax, off));
            }
            const float den = vmax - vmin;
            const float inv = (den > 0.f) ? 1.f / den : 0.f;
            double s1 = 0.0, s2 = 0.0;
            for (int b = lane; b < PP; b += 64) {
                float v = (pdrow[b] - vmin) * inv;
                rwn[a * PP + b] = v;
                int cc = cnt[b] - (b == a ? 1 : 0);
                if (cc > 0) { double dv = v; s1 += cc * dv; s2 += cc * dv * dv; }
            }
            if (lane == 0) { double v0 = (0.0 - (double)vmin) * inv; s1 += v0; s2 += v0 * v0; }
#pragma unroll
            for (int off = 32; off > 0; off >>= 1) {
                s1 += __shfl_xor(s1, off);
                s2 += __shfl_xor(s2, off);
            }
            if (lane == 0) {
                double m = s1 / (double)NN;
                double var = (s2 - (double)NN * m * m) / (double)(NN - 1);
                mu[a] = (float)m;
                sd[a] = (float)sqrt(fmax(var, 0.0));
            }
        }
    }
}

// ---- CtabT[c][p] = (c in neg_q[p]) ? exp((rwn[hq[p]][c]-mu[c])^2/(2 sd[c]^2)) : 0
// R20: p is the orig index now — nq reads are perfectly coalesced, no pi.
__global__ __launch_bounds__(256) void ctab_kernel(
    const int* __restrict__ hq, const int* __restrict__ nq,
    const float* __restrict__ rwn, const float* __restrict__ mu, const float* __restrict__ sd,
    float* __restrict__ CtabT) {
    const int p0 = blockIdx.x * 32;
    const int t = threadIdx.x;
    __shared__ unsigned long long bits[32][2];
    __shared__ int cls[32];
    __shared__ float smu[PP], ssd[PP];
    if (t < 32) {
        const int p = p0 + t;
        const int* row = nq + (size_t)p * KK;
        unsigned long long b0 = 0, b1 = 0;
#pragma unroll
        for (int k = 0; k < KK; ++k) {
            int c = row[k];
            if (c < 64) b0 |= 1ull << c; else b1 |= 1ull << (c - 64);
        }
        bits[t][0] = b0;
        bits[t][1] = b1;
        cls[t] = hq[p];
    }
    if (t < PP) { smu[t] = mu[t]; ssd[t] = sd[t]; }
    __syncthreads();
    for (int idx = t; idx < 32 * PP; idx += 256) {
        const int c = idx >> 5;
        const int pl = idx & 31;
        const bool m = (c < 64) ? ((bits[pl][0] >> c) & 1) : ((bits[pl][1] >> (c - 64)) & 1);
        float v = 0.f;
        if (m) {
            float d = rwn[cls[pl] * PP + c] - smu[c];
            float s = ssd[c];
            v = expf(d * d / (2.0f * s * s));
        }
        CtabT[(size_t)c * NN + p0 + pl] = v;
    }
}

// ---------------- symmetric fused GEMM over upper-triangular blocks ----------------
// denom = sum_{p<q} exp(5*dot_pq) * (CtabT[cls q][p] + CtabT[cls p][q])
// Tiles 128(i) x 64(j); kept: bj >= 2*bi (4160 blocks). XCD swizzle on bj&7.
// R16-verified shape: A->regs (8 lx2), B 16KB->LDS via global_load_lds, one
// barrier, K-loop from regs+LDS, hoisted column classes. Do NOT reintroduce
// per-block device fences or 128x128 tiles (R17: 3x regression).
// R19: result atomic to an XCD-private 64B line (dpart 512 slots).
// R20: classes read from hq directly (no sort); row-class int4 loads hoisted
// above the barrier (removes a dependent L2 round trip from the epilogue).
__device__ __forceinline__ void gload_lds16(void* g, void* l) {
    typedef __attribute__((address_space(1))) void* as1_void_p;
    typedef __attribute__((address_space(3))) void* as3_void_p;
    __builtin_amdgcn_global_load_lds((as1_void_p)g, (as3_void_p)l, 16, 0, 0);
}

__global__ __launch_bounds__(256) void sim_kernel(
    const char* __restrict__ Gpb, const int* __restrict__ hq,
    const float* __restrict__ CtabT, double* __restrict__ dpart) {
    const int xcd = blockIdx.x & 7;
    int idx0 = blockIdx.x >> 3;              // 0..543
    if (idx0 >= 496 + (xcd >> 1) * 16) return;  // block-uniform early exit
    int idx = idx0;
    int bj = 0, bi = 0;
#pragma unroll
    for (int q = 0; q < 16; ++q) {           // invert per-XCD triangular enumeration
        const int bjq = xcd + 8 * q;
        const int c = (bjq >> 1) + 1;
        if (idx < c) { bj = bjq; bi = idx; break; }
        idx -= c;
    }

    const int t = threadIdx.x;
    const int lane = t & 63;
    const int wv = t >> 6;
    const int i0w = bi * 128 + wv * 32;   // this wave's 32-row group base
    const int j0 = bj * 64;

    __shared__ alignas(16) char lB[16384];

    // ---- A fragments -> registers: 8 x 16B per lane, all issued up front ----
    const char* pa = Gpb + (size_t)(i0w >> 5) * 8192 + lane * 16;
    lx2 a[8];
#pragma unroll
    for (int q = 0; q < 8; ++q) a[q] = *(const lx2*)(pa + q * 1024);

    // ---- B tile: 16KB contiguous in Gpb (two 32-col groups) -> LDS, linear ----
    char* gB = const_cast<char*>(Gpb) + (size_t)(j0 >> 5) * 8192;
#pragma unroll
    for (int s = 0; s < 4; ++s) {
        const int off = (s * 4 + wv) * 1024;   // wave-uniform LDS base + lane*16
        gload_lds16(gB + off + lane * 16, lB + off);
    }

    // ---- column + row classes: independent loads, hoisted above the barrier ----
    const int cl = lane & 31, h = lane >> 5;
    const int col0 = j0 + cl;
    const int col1 = j0 + 32 + cl;
    const int cls0 = hq[col0];
    const int cls1 = hq[col1];
    int4 rcg[4];
#pragma unroll
    for (int g = 0; g < 4; ++g)
        rcg[g] = *(const int4*)(hq + i0w + 8 * g + 4 * h);   // 4 row classes per g

    __syncthreads();   // drains vmcnt(0): A in regs, B in LDS

    f32x16 acc[2] = {};
#pragma unroll
    for (int q = 0; q < 8; ++q) {
        const lx2 b0 = *(const lx2*)(lB + q * 1024 + lane * 16);          // ds_read_b128
        const lx2 b1 = *(const lx2*)(lB + 8192 + q * 1024 + lane * 16);   // conflict-free
        acc[0] = __builtin_amdgcn_mfma_f32_32x32x16_fp8_fp8(a[q].x, b0.x, acc[0], 0, 0, 0);
        acc[1] = __builtin_amdgcn_mfma_f32_32x32x16_fp8_fp8(a[q].x, b1.x, acc[1], 0, 0, 0);
        acc[0] = __builtin_amdgcn_mfma_f32_32x32x16_fp8_fp8(a[q].y, b0.y, acc[0], 0, 0, 0);
        acc[1] = __builtin_amdgcn_mfma_f32_32x32x16_fp8_fp8(a[q].y, b1.y, acc[1], 0, 0, 0);
    }

    // C/D layout (32x32): col = lane&31, row = (reg&3) + 8*(reg>>2) + 4*(lane>>5)
    const float* ct0 = CtabT + (size_t)cls0 * NN;   // coef by column class
    const float* ct1 = CtabT + (size_t)cls1 * NN;
    float partial = 0.f;
#pragma unroll
    for (int g = 0; g < 4; ++g) {
        const int rbase = i0w + 8 * g + 4 * h;
        const float4 cf0 = *(const float4*)(ct0 + rbase);   // C[row][cls col0]
        const float4 cf1 = *(const float4*)(ct1 + rbase);   // C[row][cls col1]
        const float* f0 = (const float*)&cf0;
        const float* f1 = (const float*)&cf1;
        const int rcv[4] = {rcg[g].x, rcg[g].y, rcg[g].z, rcg[g].w};
#pragma unroll
        for (int r = 0; r < 4; ++r) {
            const int row = rbase + r;
            const float* ctr = CtabT + (size_t)rcv[r] * NN;   // half-wave uniform
            const float c20 = ctr[col0];                      // coalesced over cl
            const float c21 = ctr[col1];
            const float e0 = __expf(acc[0][4 * g + r] * 5.0f);
            const float e1 = __expf(acc[1][4 * g + r] * 5.0f);
            partial += (row < col0) ? e0 * (f0[r] + c20) : 0.f;
            partial += (row < col1) ? e1 * (f1[r] + c21) : 0.f;
        }
    }
#pragma unroll
    for (int off = 32; off > 0; off >>= 1) partial += __shfl_down(partial, off);
    __shared__ float wsum[4];
    if (lane == 0) wsum[wv] = partial;
    __syncthreads();
    if (t == 0) {
        // XCD-private line: line = xcd*8 + (idx0&7); slot spreads within line
        const int slot = (xcd * 8 + (idx0 & 7)) * 8 + ((idx0 >> 3) & 7);
        atomicAdd(&dpart[slot], (double)(wsum[0] + wsum[1] + wsum[2] + wsum[3]));
    }
}

// ---------------- finalize ----------------
__global__ void finalize_kernel(const double* __restrict__ dpart,
                                const double* __restrict__ ppart, float* __restrict__ out) {
    const int lane = threadIdx.x;  // 64
    double d = 0.0, p = 0.0;
#pragma unroll
    for (int k = 0; k < 8; ++k) {
        d += dpart[lane + 64 * k];
        p += ppart[lane + 64 * k];
    }
#pragma unroll
    for (int off = 32; off > 0; off >>= 1) {
        d += __shfl_down(d, off);
        p += __shfl_down(p, off);
    }
    if (lane == 0) out[0] = (float)(log(d) - p * (5.0 / 4096.0));
}

extern "C" void kernel_launch(void* const* d_in, const int* in_sizes, int n_in,
                              void* d_out, int out_size, void* d_ws, size_t ws_size,
                              hipStream_t stream) {
    const float* x  = (const float*)d_in[0];
    const float* xa = (const float*)d_in[1];
    const float* pw = (const float*)d_in[2];
    const int* hq   = (const int*)d_in[3];
    const int* nq   = (const int*)d_in[4];
    float* out      = (float*)d_out;

    char* ws = (char*)d_ws;
    double* dpart = (double*)(ws + OFF_DPART);
    double* ppart = (double*)(ws + OFF_PPART);
    int* cnt      = (int*)(ws + OFF_CNT);
    float* mu     = (float*)(ws + OFF_MU);
    float* sd     = (float*)(ws + OFF_SD);
    float* rwn    = (float*)(ws + OFF_RWN);
    float* CtabT  = (float*)(ws + OFF_CTABT);
    char* Gpb     = (char*)(ws + OFF_G);

    prep_kernel<<<1, 1024, 0, stream>>>(hq, cnt, dpart, ppart);
    norm_protopd_kernel<<<1124, 256, 0, stream>>>(x, xa, pw, cnt, Gpb, ppart,
                                                  rwn, mu, sd);
    ctab_kernel<<<NN / 32, 256, 0, stream>>>(hq, nq, rwn, mu, sd, CtabT);
    sim_kernel<<<8 * 544, 256, 0, stream>>>(Gpb, hq, CtabT, dpart);
    finalize_kernel<<<1, 64, 0, stream>>>(dpart, ppart, out);
}

// Round 6
// 125.911 us; speedup vs baseline: 1.0875x; 1.0875x over previous
//
#include <hip/hip_runtime.h>
#include <cmath>

// Problem constants (B=4096, D=256, P=100, K=10, n=2B=8192, T=0.2)
#define BB   4096
#define DD   256
#define NN   8192
#define PP   100
#define KK   10

typedef float f32x16 __attribute__((ext_vector_type(16)));
typedef long  lx2    __attribute__((ext_vector_type(2)));

// ---------------- workspace layout (bytes) ----------------
// R19: dpart/ppart padded to 512 slots (one double per 64B line); sim's
// result lines XCD-partitioned (cross-XCD atomic ping-pong lesson).
// R21: sort RESTORED (R5 post-mortem: unsorted classes cost sim +10us /
// FETCH 11->25MB — CtabT epilogue gathers lose L2 locality). Sort scatter
// parallelized: prep = histogram+scan only; scatter_kernel (16 blocks,
// LDS-local cursors from base16) does placement. No cross-XCD atomics.
constexpr size_t OFF_DPART = 0;        // 512 double (64B-line stride)
constexpr size_t OFF_PPART = 4096;     // 512 double
constexpr size_t OFF_CNT   = 8192;     // 100 int
constexpr size_t OFF_MU    = 8704;     // 100 f32
constexpr size_t OFF_SD    = 9216;     // 100 f32
constexpr size_t OFF_RWN   = 9728;     // 10000 f32 -> 49728
constexpr size_t OFF_BASE  = 49728;    // 16*100 int (per-chunk class bases) -> 56128
constexpr size_t OFF_PI    = 56128;    // 8192 int (sorted pos -> orig)
constexpr size_t OFF_INVP  = 88896;    // 8192 int (orig -> sorted pos)
constexpr size_t OFF_HQP   = 121664;   // 8192 int (class at sorted pos)
constexpr size_t OFF_CTABT = 154432;   // 100*8192 f32 -> 3431232 (16B aligned)
constexpr size_t OFF_G     = 3431232;  // 8192*256 fp8 pair-packed (2 MB), 16B aligned

// Pair-packed fp8 G layout for mfma_f32_32x32x16_fp8_fp8 (byte addr):
// element (row p, k) at (p>>5)*8192 + (k>>5)*1024 + (((k>>3)&1)*32 + (p&31))*16
//                     + ((k>>4)&1)*8 + (k&7)
// => lane l's fragments for kc=2q,2q+1 are the contiguous 16 B at
//    (p>>5)*8192 + q*1024 + l*16   (low 8 B: kc=2q, high 8 B: kc=2q+1)

// ------ prep (1 block): zero accs, per-chunk histogram, scan -> cnt, base16 ------
__global__ __launch_bounds__(1024) void prep_kernel(
    const int* __restrict__ hq, int* __restrict__ cnt, int* __restrict__ base16,
    double* __restrict__ dpart, double* __restrict__ ppart) {
    __shared__ int h[16][PP];     // h[chunk][class], chunk = i>>9
    __shared__ int sc[PP];
    const int t = threadIdx.x;    // 1024
    h[t & 15][t >> 4] = 0;        // zero 16x100 = 1600 slots in 2 passes
    if (t < 576) h[(t + 1024) & 15][(t + 1024) >> 4] = 0;
    if (t < 512) dpart[t] = 0.0; else ppart[t - 512] = 0.0;
    __syncthreads();
#pragma unroll
    for (int r = 0; r < 8; ++r) {
        const int i = r * 1024 + t;
        atomicAdd(&h[2 * r + (t >> 9)][hq[i]], 1);
    }
    __syncthreads();
    int bb[16];
    if (t < PP) {
        int s = 0;
#pragma unroll
        for (int ch = 0; ch < 16; ++ch) { bb[ch] = s; s += h[ch][t]; }
        cnt[t] = s;
        sc[t] = s;
    }
    __syncthreads();
    if (t == 0) {
        int run = 0;
        for (int c = 0; c < PP; ++c) { int v = sc[c]; sc[c] = run; run += v; }
    }
    __syncthreads();
    if (t < PP) {
        const int cb = sc[t];
#pragma unroll
        for (int ch = 0; ch < 16; ++ch) base16[ch * PP + t] = cb + bb[ch];
    }
}

// ------ scatter (16 blocks, one per 512-sample chunk): placement via LDS cursors ------
__global__ __launch_bounds__(256) void scatter_kernel(
    const int* __restrict__ hq, const int* __restrict__ base16,
    int* __restrict__ pi, int* __restrict__ invp, int* __restrict__ hqp) {
    __shared__ int cur[PP];
    const int t = threadIdx.x;
    const int ch = blockIdx.x;
    if (t < PP) cur[t] = base16[ch * PP + t];
    __syncthreads();
#pragma unroll
    for (int r = 0; r < 2; ++r) {
        const int i = ch * 512 + r * 256 + t;
        const int c = hq[i];
        const int d = atomicAdd(&cur[c], 1);   // LDS atomic: fast, block-local
        pi[d] = i;
        hqp[d] = c;
        invp[i] = d;
    }
}

// ---- merged: blocks 0..1023 normalize (wave/sample); blocks 1024..1123 protopd ----
__global__ __launch_bounds__(256) void norm_protopd_kernel(
    const float* __restrict__ x, const float* __restrict__ xa,
    const float* __restrict__ pw, const int* __restrict__ invp,
    const int* __restrict__ cnt, char* __restrict__ Gpb, double* __restrict__ ppart,
    float* __restrict__ rwn, float* __restrict__ mu, float* __restrict__ sd) {
    const int blk = blockIdx.x;
    const int t = threadIdx.x;
    if (blk < 1024) {
        // ---- normalize role: wave per sample, barrier-free ----
        const int wv = t >> 6, lane = t & 63;
        const int i = blk * 4 + wv;            // sample 0..4095
        const float4 v1 = *(const float4*)(x  + (size_t)i * DD + lane * 4);
        const float4 v2 = *(const float4*)(xa + (size_t)i * DD + lane * 4);
        float a = v1.x * v1.x + v1.y * v1.y + v1.z * v1.z + v1.w * v1.w;
        float b = v2.x * v2.x + v2.y * v2.y + v2.z * v2.z + v2.w * v2.w;
        float c = v1.x * v2.x + v1.y * v2.y + v1.z * v2.z + v1.w * v2.w;
#pragma unroll
        for (int off = 32; off > 0; off >>= 1) {
            a += __shfl_xor(a, off);
            b += __shfl_xor(b, off);
            c += __shfl_xor(c, off);
        }
        const float d1 = fmaxf(sqrtf(a), 1e-12f), i1 = 1.0f / d1;
        const float d2 = fmaxf(sqrtf(b), 1e-12f), i2 = 1.0f / d2;
        const int p1 = invp[i];
        const int p2 = invp[i + BB];
        int w1 = __builtin_amdgcn_cvt_pk_fp8_f32(v1.x * i1, v1.y * i1, 0, false);
        w1 = __builtin_amdgcn_cvt_pk_fp8_f32(v1.z * i1, v1.w * i1, w1, true);
        int w2 = __builtin_amdgcn_cvt_pk_fp8_f32(v2.x * i2, v2.y * i2, 0, false);
        w2 = __builtin_amdgcn_cvt_pk_fp8_f32(v2.z * i2, v2.w * i2, w2, true);
        // lane l holds k0 = 4l: q=k0>>5, halfsel=(k0>>3)&1, pairsel=(k0>>4)&1
        const int q = lane >> 3, halfsel = (lane >> 1) & 1, pairsel = (lane >> 2) & 1;
        const int bo = pairsel * 8 + 4 * (lane & 1);
        const size_t a1 = (size_t)((p1 >> 5) * 8192 + q * 1024 +
                                   (halfsel * 32 + (p1 & 31)) * 16 + bo);
        const size_t a2 = (size_t)((p2 >> 5) * 8192 + q * 1024 +
                                   (halfsel * 32 + (p2 & 31)) * 16 + bo);
        *(int*)(Gpb + a1) = w1;
        *(int*)(Gpb + a2) = w2;
        // R19: one double per 64B line
        if (lane == 0) atomicAdd(&ppart[i & 511], (double)(c * i1 * i2));
    } else {
        // ---- protopd role: proto-norm row a + pd row + per-class stats ----
        const int a = blk - 1024;   // 0..99
        __shared__ alignas(16) float wa[DD];
        __shared__ float pdrow[PP];
        __shared__ float r4[4];
        float av = pw[(size_t)a * DD + t];
        float ss = av * av;
#pragma unroll
        for (int off = 32; off > 0; off >>= 1) ss += __shfl_down(ss, off);
        if ((t & 63) == 0) r4[t >> 6] = ss;
        __syncthreads();
        const float na = fmaxf(sqrtf(r4[0] + r4[1] + r4[2] + r4[3]), 1e-12f);
        wa[t] = av / na;
        __syncthreads();
        if (t < PP) {
            const float4* wc = (const float4*)(pw + (size_t)t * DD);
            float dot = 0.f, nb = 0.f;
#pragma unroll 4
            for (int k = 0; k < 64; ++k) {
                const float4 w = wc[k];
                const float4 u = *(const float4*)(wa + 4 * k);
                dot += u.x * w.x + u.y * w.y + u.z * w.z + u.w * w.w;
                nb += w.x * w.x + w.y * w.y + w.z * w.z + w.w * w.w;
            }
            pdrow[t] = 1.0f - dot / fmaxf(sqrtf(nb), 1e-12f);
        }
        __syncthreads();
        if (t < 64) {
            const int lane = t;
            float vmin = 0.f, vmax = 0.f;  // eye-zero always in multiset
            for (int b = lane; b < PP; b += 64) {
                int cc = cnt[b] - (b == a ? 1 : 0);
                if (cc > 0) {
                    float v = pdrow[b];
                    vmin = fminf(vmin, v);
                    vmax = fmaxf(vmax, v);
                }
            }
#pragma unroll
            for (int off = 32; off > 0; off >>= 1) {
                vmin = fminf(vmin, __shfl_xor(vmin, off));
                vmax = fmaxf(vmax, __shfl_xor(vmax, off));
            }
            const float den = vmax - vmin;
            const float inv = (den > 0.f) ? 1.f / den : 0.f;
            double s1 = 0.0, s2 = 0.0;
            for (int b = lane; b < PP; b += 64) {
                float v = (pdrow[b] - vmin) * inv;
                rwn[a * PP + b] = v;
                int cc = cnt[b] - (b == a ? 1 : 0);
                if (cc > 0) { double dv = v; s1 += cc * dv; s2 += cc * dv * dv; }
            }
            if (lane == 0) { double v0 = (0.0 - (double)vmin) * inv; s1 += v0; s2 += v0 * v0; }
#pragma unroll
            for (int off = 32; off > 0; off >>= 1) {
                s1 += __shfl_xor(s1, off);
                s2 += __shfl_xor(s2, off);
            }
            if (lane == 0) {
                double m = s1 / (double)NN;
                double var = (s2 - (double)NN * m * m) / (double)(NN - 1);
                mu[a] = (float)m;
                sd[a] = (float)sqrt(fmax(var, 0.0));
            }
        }
    }
}

// ---- CtabT[c][p] = (c in neg_q[pi[p]]) ? exp((rwn[hqp[p]][c]-mu[c])^2/(2 sd[c]^2)) : 0
__global__ __launch_bounds__(256) void ctab_kernel(
    const int* __restrict__ pi, const int* __restrict__ hqp, const int* __restrict__ nq,
    const float* __restrict__ rwn, const float* __restrict__ mu, const float* __restrict__ sd,
    float* __restrict__ CtabT) {
    const int p0 = blockIdx.x * 32;
    const int t = threadIdx.x;
    __shared__ unsigned long long bits[32][2];
    __shared__ int cls[32];
    __shared__ float smu[PP], ssd[PP];
    if (t < 32) {
        const int p = p0 + t;
        const int* row = nq + (size_t)pi[p] * KK;
        unsigned long long b0 = 0, b1 = 0;
#pragma unroll
        for (int k = 0; k < KK; ++k) {
            int c = row[k];
            if (c < 64) b0 |= 1ull << c; else b1 |= 1ull << (c - 64);
        }
        bits[t][0] = b0;
        bits[t][1] = b1;
        cls[t] = hqp[p];
    }
    if (t < PP) { smu[t] = mu[t]; ssd[t] = sd[t]; }
    __syncthreads();
    for (int idx = t; idx < 32 * PP; idx += 256) {
        const int c = idx >> 5;
        const int pl = idx & 31;
        const bool m = (c < 64) ? ((bits[pl][0] >> c) & 1) : ((bits[pl][1] >> (c - 64)) & 1);
        float v = 0.f;
        if (m) {
            float d = rwn[cls[pl] * PP + c] - smu[c];
            float s = ssd[c];
            v = expf(d * d / (2.0f * s * s));
        }
        CtabT[(size_t)c * NN + p0 + pl] = v;
    }
}

// ---------------- symmetric fused GEMM over upper-triangular blocks ----------------
// denom = sum_{p<q} exp(5*dot_pq) * (CtabT[cls q][p] + CtabT[cls p][q])
// Tiles 128(i) x 64(j); kept: bj >= 2*bi (4160 blocks). XCD swizzle on bj&7.
// R16-verified shape: A->regs (8 lx2), B 16KB->LDS via global_load_lds, one
// barrier, K-loop from regs+LDS, hoisted classes. Do NOT reintroduce
// per-block device fences or 128x128 tiles (R17: 3x regression).
// R19: result atomic to an XCD-private 64B line (dpart 512 slots).
// R21: class-sorted rows/cols are REQUIRED for epilogue L2 locality
// (R5 measured: unsorted = +10us, FETCH 11->25MB).
__device__ __forceinline__ void gload_lds16(void* g, void* l) {
    typedef __attribute__((address_space(1))) void* as1_void_p;
    typedef __attribute__((address_space(3))) void* as3_void_p;
    __builtin_amdgcn_global_load_lds((as1_void_p)g, (as3_void_p)l, 16, 0, 0);
}

__global__ __launch_bounds__(256) void sim_kernel(
    const char* __restrict__ Gpb, const int* __restrict__ hqp,
    const float* __restrict__ CtabT, double* __restrict__ dpart) {
    const int xcd = blockIdx.x & 7;
    int idx0 = blockIdx.x >> 3;              // 0..543
    if (idx0 >= 496 + (xcd >> 1) * 16) return;  // block-uniform early exit
    int idx = idx0;
    int bj = 0, bi = 0;
#pragma unroll
    for (int q = 0; q < 16; ++q) {           // invert per-XCD triangular enumeration
        const int bjq = xcd + 8 * q;
        const int c = (bjq >> 1) + 1;
        if (idx < c) { bj = bjq; bi = idx; break; }
        idx -= c;
    }

    const int t = threadIdx.x;
    const int lane = t & 63;
    const int wv = t >> 6;
    const int i0w = bi * 128 + wv * 32;   // this wave's 32-row group base
    const int j0 = bj * 64;

    __shared__ alignas(16) char lB[16384];

    // ---- A fragments -> registers: 8 x 16B per lane, all issued up front ----
    const char* pa = Gpb + (size_t)(i0w >> 5) * 8192 + lane * 16;
    lx2 a[8];
#pragma unroll
    for (int q = 0; q < 8; ++q) a[q] = *(const lx2*)(pa + q * 1024);

    // ---- B tile: 16KB contiguous in Gpb (two 32-col groups) -> LDS, linear ----
    char* gB = const_cast<char*>(Gpb) + (size_t)(j0 >> 5) * 8192;
#pragma unroll
    for (int s = 0; s < 4; ++s) {
        const int off = (s * 4 + wv) * 1024;   // wave-uniform LDS base + lane*16
        gload_lds16(gB + off + lane * 16, lB + off);
    }

    // ---- column + row classes: independent loads, hoisted above the barrier ----
    const int cl = lane & 31, h = lane >> 5;
    const int col0 = j0 + cl;
    const int col1 = j0 + 32 + cl;
    const int cls0 = hqp[col0];
    const int cls1 = hqp[col1];
    int4 rcg[4];
#pragma unroll
    for (int g = 0; g < 4; ++g)
        rcg[g] = *(const int4*)(hqp + i0w + 8 * g + 4 * h);   // 4 row classes per g

    __syncthreads();   // drains vmcnt(0): A in regs, B in LDS

    f32x16 acc[2] = {};
#pragma unroll
    for (int q = 0; q < 8; ++q) {
        const lx2 b0 = *(const lx2*)(lB + q * 1024 + lane * 16);          // ds_read_b128
        const lx2 b1 = *(const lx2*)(lB + 8192 + q * 1024 + lane * 16);   // conflict-free
        acc[0] = __builtin_amdgcn_mfma_f32_32x32x16_fp8_fp8(a[q].x, b0.x, acc[0], 0, 0, 0);
        acc[1] = __builtin_amdgcn_mfma_f32_32x32x16_fp8_fp8(a[q].x, b1.x, acc[1], 0, 0, 0);
        acc[0] = __builtin_amdgcn_mfma_f32_32x32x16_fp8_fp8(a[q].y, b0.y, acc[0], 0, 0, 0);
        acc[1] = __builtin_amdgcn_mfma_f32_32x32x16_fp8_fp8(a[q].y, b1.y, acc[1], 0, 0, 0);
    }

    // C/D layout (32x32): col = lane&31, row = (reg&3) + 8*(reg>>2) + 4*(lane>>5)
    const float* ct0 = CtabT + (size_t)cls0 * NN;   // coef by column class
    const float* ct1 = CtabT + (size_t)cls1 * NN;
    float partial = 0.f;
#pragma unroll
    for (int g = 0; g < 4; ++g) {
        const int rbase = i0w + 8 * g + 4 * h;
        const float4 cf0 = *(const float4*)(ct0 + rbase);   // C[row][cls col0]
        const float4 cf1 = *(const float4*)(ct1 + rbase);   // C[row][cls col1]
        const float* f0 = (const float*)&cf0;
        const float* f1 = (const float*)&cf1;
        const int rcv[4] = {rcg[g].x, rcg[g].y, rcg[g].z, rcg[g].w};
#pragma unroll
        for (int r = 0; r < 4; ++r) {
            const int row = rbase + r;
            const float* ctr = CtabT + (size_t)rcv[r] * NN;   // half-wave uniform
            const float c20 = ctr[col0];                      // coalesced over cl
            const float c21 = ctr[col1];
            const float e0 = __expf(acc[0][4 * g + r] * 5.0f);
            const float e1 = __expf(acc[1][4 * g + r] * 5.0f);
            partial += (row < col0) ? e0 * (f0[r] + c20) : 0.f;
            partial += (row < col1) ? e1 * (f1[r] + c21) : 0.f;
        }
    }
#pragma unroll
    for (int off = 32; off > 0; off >>= 1) partial += __shfl_down(partial, off);
    __shared__ float wsum[4];
    if (lane == 0) wsum[wv] = partial;
    __syncthreads();
    if (t == 0) {
        // XCD-private line: line = xcd*8 + (idx0&7); slot spreads within line
        const int slot = (xcd * 8 + (idx0 & 7)) * 8 + ((idx0 >> 3) & 7);
        atomicAdd(&dpart[slot], (double)(wsum[0] + wsum[1] + wsum[2] + wsum[3]));
    }
}

// ---------------- finalize ----------------
__global__ void finalize_kernel(const double* __restrict__ dpart,
                                const double* __restrict__ ppart, float* __restrict__ out) {
    const int lane = threadIdx.x;  // 64
    double d = 0.0, p = 0.0;
#pragma unroll
    for (int k = 0; k < 8; ++k) {
        d += dpart[lane + 64 * k];
        p += ppart[lane + 64 * k];
    }
#pragma unroll
    for (int off = 32; off > 0; off >>= 1) {
        d += __shfl_down(d, off);
        p += __shfl_down(p, off);
    }
    if (lane == 0) out[0] = (float)(log(d) - p * (5.0 / 4096.0));
}

extern "C" void kernel_launch(void* const* d_in, const int* in_sizes, int n_in,
                              void* d_out, int out_size, void* d_ws, size_t ws_size,
                              hipStream_t stream) {
    const float* x  = (const float*)d_in[0];
    const float* xa = (const float*)d_in[1];
    const float* pw = (const float*)d_in[2];
    const int* hq   = (const int*)d_in[3];
    const int* nq   = (const int*)d_in[4];
    float* out      = (float*)d_out;

    char* ws = (char*)d_ws;
    double* dpart = (double*)(ws + OFF_DPART);
    double* ppart = (double*)(ws + OFF_PPART);
    int* cnt      = (int*)(ws + OFF_CNT);
    float* mu     = (float*)(ws + OFF_MU);
    float* sd     = (float*)(ws + OFF_SD);
    float* rwn    = (float*)(ws + OFF_RWN);
    int* base16   = (int*)(ws + OFF_BASE);
    int* pi       = (int*)(ws + OFF_PI);
    int* invp     = (int*)(ws + OFF_INVP);
    int* hqp      = (int*)(ws + OFF_HQP);
    float* CtabT  = (float*)(ws + OFF_CTABT);
    char* Gpb     = (char*)(ws + OFF_G);

    prep_kernel<<<1, 1024, 0, stream>>>(hq, cnt, base16, dpart, ppart);
    scatter_kernel<<<16, 256, 0, stream>>>(hq, base16, pi, invp, hqp);
    norm_protopd_kernel<<<1124, 256, 0, stream>>>(x, xa, pw, invp, cnt, Gpb, ppart,
                                                  rwn, mu, sd);
    ctab_kernel<<<NN / 32, 256, 0, stream>>>(pi, hqp, nq, rwn, mu, sd, CtabT);
    sim_kernel<<<8 * 544, 256, 0, stream>>>(Gpb, hqp, CtabT, dpart);
    finalize_kernel<<<1, 64, 0, stream>>>(dpart, ppart, out);
}

// Round 7
// 123.380 us; speedup vs baseline: 1.1098x; 1.0205x over previous
//
#include <hip/hip_runtime.h>
#include <cmath>

// Problem constants (B=4096, D=256, P=100, K=10, n=2B=8192, T=0.2)
#define BB   4096
#define DD   256
#define NN   8192
#define PP   100
#define KK   10

typedef float f32x16 __attribute__((ext_vector_type(16)));
typedef long  lx2    __attribute__((ext_vector_type(2)));

// ---------------- workspace layout (bytes) ----------------
// R19: dpart/ppart padded to 512 slots (one double per 64B line); sim's
// result lines XCD-partitioned (cross-XCD atomic ping-pong lesson).
// R21: class-sorted order REQUIRED (R5: unsorted cost sim +10us, FETCH 11->25MB).
// R22: prep+scatter merged into sortzero (17 blocks, redundant histograms);
// norm 4 samples/wave; sim epilogue operands batched into register arrays.
constexpr size_t OFF_DPART = 0;        // 512 double (64B-line stride)
constexpr size_t OFF_PPART = 4096;     // 512 double
constexpr size_t OFF_CNT   = 8192;     // 100 int
constexpr size_t OFF_MU    = 8704;     // 100 f32
constexpr size_t OFF_SD    = 9216;     // 100 f32
constexpr size_t OFF_RWN   = 9728;     // 10000 f32 -> 49728
constexpr size_t OFF_PI    = 56128;    // 8192 int (sorted pos -> orig)
constexpr size_t OFF_INVP  = 88896;    // 8192 int (orig -> sorted pos)
constexpr size_t OFF_HQP   = 121664;   // 8192 int (class at sorted pos)
constexpr size_t OFF_CTABT = 154432;   // 100*8192 f32 -> 3431232 (16B aligned)
constexpr size_t OFF_G     = 3431232;  // 8192*256 fp8 pair-packed (2 MB), 16B aligned

// Pair-packed fp8 G layout for mfma_f32_32x32x16_fp8_fp8 (byte addr):
// element (row p, k) at (p>>5)*8192 + (k>>5)*1024 + (((k>>3)&1)*32 + (p&31))*16
//                     + ((k>>4)&1)*8 + (k&7)
// => lane l's fragments for kc=2q,2q+1 are the contiguous 16 B at
//    (p>>5)*8192 + q*1024 + l*16   (low 8 B: kc=2q, high 8 B: kc=2q+1)

// ------ sortzero (17 blocks): counting sort (blocks 0..15) + zero/cnt (block 16) ------
// Each sort block redundantly histograms ALL of hq (32KB, L2-hot) into
// per-chunk counts, scans locally, and places its own 512-sample chunk with
// block-local LDS cursors. No cross-block deps, no cross-XCD atomics.
__global__ __launch_bounds__(256) void sortzero_kernel(
    const int* __restrict__ hq, int* __restrict__ cnt,
    int* __restrict__ pi, int* __restrict__ invp, int* __restrict__ hqp,
    double* __restrict__ dpart, double* __restrict__ ppart) {
    const int blk = blockIdx.x;
    const int t = threadIdx.x;   // 256
    if (blk == 16) {
        // zero accumulators + class totals for protopd
        for (int k = t; k < 512; k += 256) { dpart[k] = 0.0; ppart[k] = 0.0; }
        __shared__ int hh[PP];
        if (t < PP) hh[t] = 0;
        __syncthreads();
#pragma unroll
        for (int r = 0; r < 32; ++r) atomicAdd(&hh[hq[r * 256 + t]], 1);
        __syncthreads();
        if (t < PP) cnt[t] = hh[t];
        return;
    }
    __shared__ int h[16][PP];    // h[chunk][class], chunk = i>>9
    __shared__ int tot[PP];
    __shared__ int gbase[PP];
    __shared__ int base[PP];     // doubles as cursor
    int* hf = &h[0][0];
    for (int k = t; k < 16 * PP; k += 256) hf[k] = 0;
    __syncthreads();
#pragma unroll
    for (int r = 0; r < 32; ++r) {
        const int i = r * 256 + t;
        atomicAdd(&h[r >> 1][hq[i]], 1);   // chunk = i>>9 = r>>1
    }
    __syncthreads();
    if (t < PP) {
        int pre = 0, s = 0;
#pragma unroll
        for (int ch = 0; ch < 16; ++ch) {
            if (ch == blk) pre = s;
            s += h[ch][t];
        }
        tot[t] = s;
        base[t] = pre;           // within-class offset of this chunk
    }
    __syncthreads();
    if (t == 0) {
        int run = 0;
        for (int c = 0; c < PP; ++c) { gbase[c] = run; run += tot[c]; }
    }
    __syncthreads();
    if (t < PP) base[t] += gbase[t];
    __syncthreads();
#pragma unroll
    for (int r = 0; r < 2; ++r) {
        const int i = blk * 512 + r * 256 + t;
        const int c = hq[i];
        const int d = atomicAdd(&base[c], 1);   // LDS atomic: block-local
        pi[d] = i;
        hqp[d] = c;
        invp[i] = d;
    }
}

// ---- merged: blocks 0..255 normalize (wave = 4 samples); 256..355 protopd ----
__global__ __launch_bounds__(256) void norm_protopd_kernel(
    const float* __restrict__ x, const float* __restrict__ xa,
    const float* __restrict__ pw, const int* __restrict__ invp,
    const int* __restrict__ cnt, char* __restrict__ Gpb, double* __restrict__ ppart,
    float* __restrict__ rwn, float* __restrict__ mu, float* __restrict__ sd) {
    const int blk = blockIdx.x;
    const int t = threadIdx.x;
    if (blk < 256) {
        // ---- normalize role: wave handles 4 samples (w, w+1024, ...), all
        // loads hoisted into arrays for MLP; one ppart atomic per wave ----
        const int wv = t >> 6, lane = t & 63;
        const int w = blk * 4 + wv;            // wave id 0..1023
        float4 v1[4], v2[4];
        int p1[4], p2[4];
#pragma unroll
        for (int s = 0; s < 4; ++s) {
            const int i = w + 1024 * s;
            v1[s] = *(const float4*)(x  + (size_t)i * DD + lane * 4);
            v2[s] = *(const float4*)(xa + (size_t)i * DD + lane * 4);
            p1[s] = invp[i];
            p2[s] = invp[i + BB];
        }
        // lane l holds k0 = 4l: q=k0>>5, halfsel=(k0>>3)&1, pairsel=(k0>>4)&1
        const int q = lane >> 3, halfsel = (lane >> 1) & 1, pairsel = (lane >> 2) & 1;
        const int bo = pairsel * 8 + 4 * (lane & 1);
        double psum = 0.0;
#pragma unroll
        for (int s = 0; s < 4; ++s) {
            float a = v1[s].x * v1[s].x + v1[s].y * v1[s].y + v1[s].z * v1[s].z + v1[s].w * v1[s].w;
            float b = v2[s].x * v2[s].x + v2[s].y * v2[s].y + v2[s].z * v2[s].z + v2[s].w * v2[s].w;
            float c = v1[s].x * v2[s].x + v1[s].y * v2[s].y + v1[s].z * v2[s].z + v1[s].w * v2[s].w;
#pragma unroll
            for (int off = 32; off > 0; off >>= 1) {
                a += __shfl_xor(a, off);
                b += __shfl_xor(b, off);
                c += __shfl_xor(c, off);
            }
            const float d1 = fmaxf(sqrtf(a), 1e-12f), i1 = 1.0f / d1;
            const float d2 = fmaxf(sqrtf(b), 1e-12f), i2 = 1.0f / d2;
            int w1 = __builtin_amdgcn_cvt_pk_fp8_f32(v1[s].x * i1, v1[s].y * i1, 0, false);
            w1 = __builtin_amdgcn_cvt_pk_fp8_f32(v1[s].z * i1, v1[s].w * i1, w1, true);
            int w2 = __builtin_amdgcn_cvt_pk_fp8_f32(v2[s].x * i2, v2[s].y * i2, 0, false);
            w2 = __builtin_amdgcn_cvt_pk_fp8_f32(v2[s].z * i2, v2[s].w * i2, w2, true);
            const size_t a1 = (size_t)((p1[s] >> 5) * 8192 + q * 1024 +
                                       (halfsel * 32 + (p1[s] & 31)) * 16 + bo);
            const size_t a2 = (size_t)((p2[s] >> 5) * 8192 + q * 1024 +
                                       (halfsel * 32 + (p2[s] & 31)) * 16 + bo);
            *(int*)(Gpb + a1) = w1;
            *(int*)(Gpb + a2) = w2;
            psum += (double)(c * i1 * i2);
        }
        // R19: one double per 64B line
        if (lane == 0) atomicAdd(&ppart[w & 511], psum);
    } else {
        // ---- protopd role: proto-norm row a + pd row + per-class stats ----
        const int a = blk - 256;   // 0..99
        __shared__ alignas(16) float wa[DD];
        __shared__ float pdrow[PP];
        __shared__ float r4[4];
        float av = pw[(size_t)a * DD + t];
        float ss = av * av;
#pragma unroll
        for (int off = 32; off > 0; off >>= 1) ss += __shfl_down(ss, off);
        if ((t & 63) == 0) r4[t >> 6] = ss;
        __syncthreads();
        const float na = fmaxf(sqrtf(r4[0] + r4[1] + r4[2] + r4[3]), 1e-12f);
        wa[t] = av / na;
        __syncthreads();
        if (t < PP) {
            const float4* wc = (const float4*)(pw + (size_t)t * DD);
            float dot = 0.f, nb = 0.f;
#pragma unroll 4
            for (int k = 0; k < 64; ++k) {
                const float4 w = wc[k];
                const float4 u = *(const float4*)(wa + 4 * k);
                dot += u.x * w.x + u.y * w.y + u.z * w.z + u.w * w.w;
                nb += w.x * w.x + w.y * w.y + w.z * w.z + w.w * w.w;
            }
            pdrow[t] = 1.0f - dot / fmaxf(sqrtf(nb), 1e-12f);
        }
        __syncthreads();
        if (t < 64) {
            const int lane = t;
            float vmin = 0.f, vmax = 0.f;  // eye-zero always in multiset
            for (int b = lane; b < PP; b += 64) {
                int cc = cnt[b] - (b == a ? 1 : 0);
                if (cc > 0) {
                    float v = pdrow[b];
                    vmin = fminf(vmin, v);
                    vmax = fmaxf(vmax, v);
                }
            }
#pragma unroll
            for (int off = 32; off > 0; off >>= 1) {
                vmin = fminf(vmin, __shfl_xor(vmin, off));
                vmax = fmaxf(vmax, __shfl_xor(vmax, off));
            }
            const float den = vmax - vmin;
            const float inv = (den > 0.f) ? 1.f / den : 0.f;
            double s1 = 0.0, s2 = 0.0;
            for (int b = lane; b < PP; b += 64) {
                float v = (pdrow[b] - vmin) * inv;
                rwn[a * PP + b] = v;
                int cc = cnt[b] - (b == a ? 1 : 0);
                if (cc > 0) { double dv = v; s1 += cc * dv; s2 += cc * dv * dv; }
            }
            if (lane == 0) { double v0 = (0.0 - (double)vmin) * inv; s1 += v0; s2 += v0 * v0; }
#pragma unroll
            for (int off = 32; off > 0; off >>= 1) {
                s1 += __shfl_xor(s1, off);
                s2 += __shfl_xor(s2, off);
            }
            if (lane == 0) {
                double m = s1 / (double)NN;
                double var = (s2 - (double)NN * m * m) / (double)(NN - 1);
                mu[a] = (float)m;
                sd[a] = (float)sqrt(fmax(var, 0.0));
            }
        }
    }
}

// ---- CtabT[c][p] = (c in neg_q[pi[p]]) ? exp((rwn[hqp[p]][c]-mu[c])^2/(2 sd[c]^2)) : 0
__global__ __launch_bounds__(256) void ctab_kernel(
    const int* __restrict__ pi, const int* __restrict__ hqp, const int* __restrict__ nq,
    const float* __restrict__ rwn, const float* __restrict__ mu, const float* __restrict__ sd,
    float* __restrict__ CtabT) {
    const int p0 = blockIdx.x * 32;
    const int t = threadIdx.x;
    __shared__ unsigned long long bits[32][2];
    __shared__ int cls[32];
    __shared__ float smu[PP], ssd[PP];
    if (t < 32) {
        const int p = p0 + t;
        const int* row = nq + (size_t)pi[p] * KK;
        unsigned long long b0 = 0, b1 = 0;
#pragma unroll
        for (int k = 0; k < KK; ++k) {
            int c = row[k];
            if (c < 64) b0 |= 1ull << c; else b1 |= 1ull << (c - 64);
        }
        bits[t][0] = b0;
        bits[t][1] = b1;
        cls[t] = hqp[p];
    }
    if (t < PP) { smu[t] = mu[t]; ssd[t] = sd[t]; }
    __syncthreads();
    for (int idx = t; idx < 32 * PP; idx += 256) {
        const int c = idx >> 5;
        const int pl = idx & 31;
        const bool m = (c < 64) ? ((bits[pl][0] >> c) & 1) : ((bits[pl][1] >> (c - 64)) & 1);
        float v = 0.f;
        if (m) {
            float d = rwn[cls[pl] * PP + c] - smu[c];
            float s = ssd[c];
            v = expf(d * d / (2.0f * s * s));
        }
        CtabT[(size_t)c * NN + p0 + pl] = v;
    }
}

// ---------------- symmetric fused GEMM over upper-triangular blocks ----------------
// denom = sum_{p<q} exp(5*dot_pq) * (CtabT[cls q][p] + CtabT[cls p][q])
// Tiles 128(i) x 64(j); kept: bj >= 2*bi (4160 blocks). XCD swizzle on bj&7.
// R16-verified shape: A->regs (8 lx2), B 16KB->LDS via global_load_lds, one
// barrier, K-loop from regs+LDS, hoisted classes. Do NOT reintroduce
// per-block device fences or 128x128 tiles (R17: 3x regression).
// R19: result atomic to an XCD-private 64B line (dpart 512 slots).
// R22: epilogue operands (8 cf float4 + 32 c2 gathers) batched into explicit
// register arrays issued in one burst after the K-loop — VGPR_Count 60 meant
// the compiler had serialized these ~40 L2 loads (same pathology as R0's
// K-loop). Expected VGPR ~130.
__device__ __forceinline__ void gload_lds16(void* g, void* l) {
    typedef __attribute__((address_space(1))) void* as1_void_p;
    typedef __attribute__((address_space(3))) void* as3_void_p;
    __builtin_amdgcn_global_load_lds((as1_void_p)g, (as3_void_p)l, 16, 0, 0);
}

__global__ __launch_bounds__(256) void sim_kernel(
    const char* __restrict__ Gpb, const int* __restrict__ hqp,
    const float* __restrict__ CtabT, double* __restrict__ dpart) {
    const int xcd = blockIdx.x & 7;
    int idx0 = blockIdx.x >> 3;              // 0..543
    if (idx0 >= 496 + (xcd >> 1) * 16) return;  // block-uniform early exit
    int idx = idx0;
    int bj = 0, bi = 0;
#pragma unroll
    for (int q = 0; q < 16; ++q) {           // invert per-XCD triangular enumeration
        const int bjq = xcd + 8 * q;
        const int c = (bjq >> 1) + 1;
        if (idx < c) { bj = bjq; bi = idx; break; }
        idx -= c;
    }

    const int t = threadIdx.x;
    const int lane = t & 63;
    const int wv = t >> 6;
    const int i0w = bi * 128 + wv * 32;   // this wave's 32-row group base
    const int j0 = bj * 64;

    __shared__ alignas(16) char lB[16384];

    // ---- A fragments -> registers: 8 x 16B per lane, all issued up front ----
    const char* pa = Gpb + (size_t)(i0w >> 5) * 8192 + lane * 16;
    lx2 a[8];
#pragma unroll
    for (int q = 0; q < 8; ++q) a[q] = *(const lx2*)(pa + q * 1024);

    // ---- B tile: 16KB contiguous in Gpb (two 32-col groups) -> LDS, linear ----
    char* gB = const_cast<char*>(Gpb) + (size_t)(j0 >> 5) * 8192;
#pragma unroll
    for (int s = 0; s < 4; ++s) {
        const int off = (s * 4 + wv) * 1024;   // wave-uniform LDS base + lane*16
        gload_lds16(gB + off + lane * 16, lB + off);
    }

    // ---- column + row classes: independent loads, hoisted above the barrier ----
    const int cl = lane & 31, h = lane >> 5;
    const int col0 = j0 + cl;
    const int col1 = j0 + 32 + cl;
    const int cls0 = hqp[col0];
    const int cls1 = hqp[col1];
    int4 rcg[4];
#pragma unroll
    for (int g = 0; g < 4; ++g)
        rcg[g] = *(const int4*)(hqp + i0w + 8 * g + 4 * h);   // 4 row classes per g

    __syncthreads();   // drains vmcnt(0): A in regs, B in LDS

    f32x16 acc[2] = {};
#pragma unroll
    for (int q = 0; q < 8; ++q) {
        const lx2 b0 = *(const lx2*)(lB + q * 1024 + lane * 16);          // ds_read_b128
        const lx2 b1 = *(const lx2*)(lB + 8192 + q * 1024 + lane * 16);   // conflict-free
        acc[0] = __builtin_amdgcn_mfma_f32_32x32x16_fp8_fp8(a[q].x, b0.x, acc[0], 0, 0, 0);
        acc[1] = __builtin_amdgcn_mfma_f32_32x32x16_fp8_fp8(a[q].x, b1.x, acc[1], 0, 0, 0);
        acc[0] = __builtin_amdgcn_mfma_f32_32x32x16_fp8_fp8(a[q].y, b0.y, acc[0], 0, 0, 0);
        acc[1] = __builtin_amdgcn_mfma_f32_32x32x16_fp8_fp8(a[q].y, b1.y, acc[1], 0, 0, 0);
    }

    // ---- R22 epilogue: batch ALL operand loads (independent), then pure math ----
    // C/D layout (32x32): col = lane&31, row = (reg&3) + 8*(reg>>2) + 4*(lane>>5)
    const float* ct0 = CtabT + (size_t)cls0 * NN;   // coef by column class
    const float* ct1 = CtabT + (size_t)cls1 * NN;
    float4 cf0[4], cf1[4];
    float c20[4][4], c21[4][4];
#pragma unroll
    for (int g = 0; g < 4; ++g) {
        const int rbase = i0w + 8 * g + 4 * h;
        cf0[g] = *(const float4*)(ct0 + rbase);   // C[row][cls col0]
        cf1[g] = *(const float4*)(ct1 + rbase);   // C[row][cls col1]
        const int rcv[4] = {rcg[g].x, rcg[g].y, rcg[g].z, rcg[g].w};
#pragma unroll
        for (int r = 0; r < 4; ++r) {
            const float* ctr = CtabT + (size_t)rcv[r] * NN;   // half-wave uniform
            c20[g][r] = ctr[col0];                            // coalesced over cl
            c21[g][r] = ctr[col1];
        }
    }
    float partial = 0.f;
#pragma unroll
    for (int g = 0; g < 4; ++g) {
        const int rbase = i0w + 8 * g + 4 * h;
        const float* f0 = (const float*)&cf0[g];
        const float* f1 = (const float*)&cf1[g];
#pragma unroll
        for (int r = 0; r < 4; ++r) {
            const int row = rbase + r;
            const float e0 = __expf(acc[0][4 * g + r] * 5.0f);
            const float e1 = __expf(acc[1][4 * g + r] * 5.0f);
            partial += (row < col0) ? e0 * (f0[r] + c20[g][r]) : 0.f;
            partial += (row < col1) ? e1 * (f1[r] + c21[g][r]) : 0.f;
        }
    }
#pragma unroll
    for (int off = 32; off > 0; off >>= 1) partial += __shfl_down(partial, off);
    __shared__ float wsum[4];
    if (lane == 0) wsum[wv] = partial;
    __syncthreads();
    if (t == 0) {
        // XCD-private line: line = xcd*8 + (idx0&7); slot spreads within line
        const int slot = (xcd * 8 + (idx0 & 7)) * 8 + ((idx0 >> 3) & 7);
        atomicAdd(&dpart[slot], (double)(wsum[0] + wsum[1] + wsum[2] + wsum[3]));
    }
}

// ---------------- finalize ----------------
__global__ void finalize_kernel(const double* __restrict__ dpart,
                                const double* __restrict__ ppart, float* __restrict__ out) {
    const int lane = threadIdx.x;  // 64
    double d = 0.0, p = 0.0;
#pragma unroll
    for (int k = 0; k < 8; ++k) {
        d += dpart[lane + 64 * k];
        p += ppart[lane + 64 * k];
    }
#pragma unroll
    for (int off = 32; off > 0; off >>= 1) {
        d += __shfl_down(d, off);
        p += __shfl_down(p, off);
    }
    if (lane == 0) out[0] = (float)(log(d) - p * (5.0 / 4096.0));
}

extern "C" void kernel_launch(void* const* d_in, const int* in_sizes, int n_in,
                              void* d_out, int out_size, void* d_ws, size_t ws_size,
                              hipStream_t stream) {
    const float* x  = (const float*)d_in[0];
    const float* xa = (const float*)d_in[1];
    const float* pw = (const float*)d_in[2];
    const int* hq   = (const int*)d_in[3];
    const int* nq   = (const int*)d_in[4];
    float* out      = (float*)d_out;

    char* ws = (char*)d_ws;
    double* dpart = (double*)(ws + OFF_DPART);
    double* ppart = (double*)(ws + OFF_PPART);
    int* cnt      = (int*)(ws + OFF_CNT);
    float* mu     = (float*)(ws + OFF_MU);
    float* sd     = (float*)(ws + OFF_SD);
    float* rwn    = (float*)(ws + OFF_RWN);
    int* pi       = (int*)(ws + OFF_PI);
    int* invp     = (int*)(ws + OFF_INVP);
    int* hqp      = (int*)(ws + OFF_HQP);
    float* CtabT  = (float*)(ws + OFF_CTABT);
    char* Gpb     = (char*)(ws + OFF_G);

    sortzero_kernel<<<17, 256, 0, stream>>>(hq, cnt, pi, invp, hqp, dpart, ppart);
    norm_protopd_kernel<<<356, 256, 0, stream>>>(x, xa, pw, invp, cnt, Gpb, ppart,
                                                 rwn, mu, sd);
    ctab_kernel<<<NN / 32, 256, 0, stream>>>(pi, hqp, nq, rwn, mu, sd, CtabT);
    sim_kernel<<<8 * 544, 256, 0, stream>>>(Gpb, hqp, CtabT, dpart);
    finalize_kernel<<<1, 64, 0, stream>>>(dpart, ppart, out);
}